// Round 7
// baseline (684.624 us; speedup 1.0000x reference)
//
#include <hip/hip_runtime.h>
#include <hip/hip_bf16.h>
#include <cstdint>

#define H 128
#define VV 100
#define CC 1000
#define ER_N 250
#define NODE_IN_N 82
#define EDGE_IN_N 6
#define MROWS 112   // 7 m-tiles of 16
#define LDA 136     // bf16 row stride: keeps b128 16B-aligned, 2-way banks (free)
#define NT 1024     // 16 waves per block

typedef short short8 __attribute__((ext_vector_type(8)));
typedef float floatx4 __attribute__((ext_vector_type(4)));
typedef __hip_bfloat16 bf16;

// ================= prep: weights -> B-frag bf16; Xp -> bf16 padded; Epe -> padded =====
// segment A: 27*4096 weight frag elems; B: Xp as 100000*48 bf16x2 pairs; C: Epe 250000*8
#define PREP_W (27 * 4096)
#define PREP_X (NP_TOT * 48)
#define NP_TOT 100000
__global__ __launch_bounds__(256) void prep_all(
    const float* __restrict__ Wp, const float* __restrict__ Wm,
    const float* __restrict__ Wn, const float* __restrict__ Wmd,
    const float* __restrict__ Wnd, const float* __restrict__ Xp,
    const float* __restrict__ Epe,
    bf16* __restrict__ wfrag, bf16* __restrict__ Xbf, float* __restrict__ Epad) {
  long idx = (long)blockIdx.x * 256 + threadIdx.x;
  if (idx < PREP_W) {
    const float* W;
    int Ksrc;
    long local = idx;
    if (idx < 3 * 4096)       { W = Wp;  Ksrc = NODE_IN_N; }
    else if (idx < 7 * 4096)  { W = Wm;  Ksrc = H;     local -= 3 * 4096; }
    else if (idx < 15 * 4096) { W = Wn;  Ksrc = 2 * H; local -= 7 * 4096; }
    else if (idx < 19 * 4096) { W = Wmd; Ksrc = H;     local -= 15 * 4096; }
    else                      { W = Wnd; Ksrc = 2 * H; local -= 19 * 4096; }
    int j = local & 7, lane = (local >> 3) & 63, nt = (local >> 9) & 7, kc = local >> 12;
    int k = kc * 32 + ((lane >> 4) & 3) * 8 + j;
    int n = nt * 16 + (lane & 15);
    float v = (k < Ksrc) ? W[(size_t)k * H + n] : 0.f;
    wfrag[idx] = __float2bfloat16(v);
    return;
  }
  idx -= PREP_W;
  if (idx < (long)PREP_X) {  // bf16 pairs: row r, cols 2p,2p+1 of 96
    long r = idx / 48;
    int p = (int)(idx - r * 48);
    int c0 = 2 * p;
    float v0 = (c0 < NODE_IN_N) ? Xp[r * NODE_IN_N + c0] : 0.f;
    float v1 = (c0 + 1 < NODE_IN_N) ? Xp[r * NODE_IN_N + c0 + 1] : 0.f;
    __hip_bfloat162 pk;
    pk.x = __float2bfloat16(v0);
    pk.y = __float2bfloat16(v1);
    *(__hip_bfloat162*)&Xbf[r * 96 + c0] = pk;
    return;
  }
  idx -= (long)PREP_X;
  if (idx < (long)NP_TOT * 20) {  // 250000 edges * 8 floats
    long e = idx >> 3;
    int k = (int)(idx & 7);
    Epad[idx] = (k < EDGE_IN_N) ? Epe[e * EDGE_IN_N + k] : 0.f;
  }
}

// ================= GEMM helpers: wave=(mt, gh); per wave 1 m-tile x 4 n-tiles ========
template<int CHUNKS>
__device__ __forceinline__ void load_afrag(short8 a[CHUNKS], const bf16* A,
                                           int mt, int l16, int quad) {
#pragma unroll
  for (int kc = 0; kc < CHUNKS; ++kc)
    a[kc] = *(const short8*)(A + (mt * 16 + l16) * LDA + kc * 32 + quad * 8);
}

template<int CHUNKS>
__device__ __forceinline__ void mfma_rows(floatx4 acc[4], const short8 a[CHUNKS],
                                          const bf16* __restrict__ Wf,
                                          int gh, int lane) {
#pragma unroll
  for (int kc = 0; kc < CHUNKS; ++kc)
#pragma unroll
    for (int nt = 0; nt < 4; ++nt) {
      short8 b = *(const short8*)(Wf + ((size_t)((kc * 8 + gh * 4 + nt) * 64 + lane)) * 8);
      acc[nt] = __builtin_amdgcn_mfma_f32_16x16x32_bf16(a[kc], b, acc[nt], 0, 0, 0);
    }
}

__device__ __forceinline__ void epi(floatx4 acc[4], const float* __restrict__ bias,
                                    bool relu, bf16* Out,
                                    int mt, int gh, int quad, int l16) {
#pragma unroll
  for (int nt = 0; nt < 4; ++nt) {
    int col = (gh * 4 + nt) * 16 + l16;
    float bb = bias[col];
#pragma unroll
    for (int r = 0; r < 4; ++r) {
      float v = acc[nt][r] + bb;
      if (relu) v = fmaxf(v, 0.f);
      Out[(mt * 16 + quad * 4 + r) * LDA + col] = __float2bfloat16(v);
    }
  }
}

__device__ __forceinline__ void zero4(floatx4 acc[4]) {
#pragma unroll
  for (int nt = 0; nt < 4; ++nt) acc[nt] = (floatx4){0.f, 0.f, 0.f, 0.f};
}

// gather: thread (node q16+16i, col-pair c2) writes agg directly to sAgg
__device__ __forceinline__ void gather(const bf16* sT, bf16* sAgg, const float* sEf,
                                       const int* sRowPtr, const int* sEidx,
                                       const float* __restrict__ WmBot,
                                       int q16, int c2) {
  float wb[EDGE_IN_N][2];
#pragma unroll
  for (int k = 0; k < EDGE_IN_N; ++k) {
    float2 w2 = *(const float2*)&WmBot[k * H + 2 * c2];
    wb[k][0] = w2.x;
    wb[k][1] = w2.y;
  }
#pragma unroll
  for (int i = 0; i < 7; ++i) {
    int n = q16 + 16 * i;
    if (n < VV) {
      int p0 = sRowPtr[n], p1 = sRowPtr[n + 1];
      float a0 = 0.f, a1 = 0.f;
      for (int p = p0; p < p1; ++p) {
        int v = sEidx[p];
        int s = v & 127, e = v >> 7;
        uint32_t tt = *(const uint32_t*)&sT[s * LDA + 2 * c2];
        float u0 = __uint_as_float((tt & 0xffffu) << 16);
        float u1 = __uint_as_float((tt >> 16) << 16);
        float4 ea = *(const float4*)&sEf[e * 8];
        float2 eb = *(const float2*)&sEf[e * 8 + 4];
        u0 = fmaf(ea.x, wb[0][0], u0); u1 = fmaf(ea.x, wb[0][1], u1);
        u0 = fmaf(ea.y, wb[1][0], u0); u1 = fmaf(ea.y, wb[1][1], u1);
        u0 = fmaf(ea.z, wb[2][0], u0); u1 = fmaf(ea.z, wb[2][1], u1);
        u0 = fmaf(ea.w, wb[3][0], u0); u1 = fmaf(ea.w, wb[3][1], u1);
        u0 = fmaf(eb.x, wb[4][0], u0); u1 = fmaf(eb.x, wb[4][1], u1);
        u0 = fmaf(eb.y, wb[5][0], u0); u1 = fmaf(eb.y, wb[5][1], u1);
        a0 += fmaxf(u0, 0.f);
        a1 += fmaxf(u1, 0.f);
      }
      __hip_bfloat162 pk;
      pk.x = __float2bfloat16(a0);
      pk.y = __float2bfloat16(a1);
      *(__hip_bfloat162*)&sAgg[n * LDA + 2 * c2] = pk;
    }
  }
}

// one WLN layer: 3 barriers; A-frags loaded once, reused for msg and update-h GEMMs.
__device__ __forceinline__ void wln_layer(
    bf16* sH, bf16* sT, bf16* sAgg, const float* sEf,
    const int* sRowPtr, const int* sEidx,
    const bf16* __restrict__ wf_msg, const float* __restrict__ bmsg,
    const float* __restrict__ WmBot,
    const bf16* __restrict__ wf_new, const float* __restrict__ bnew,
    bool active, int lane, int mt, int gh, int quad, int l16, int q16, int c2) {
  short8 a[4];
  floatx4 accM[4], accU[4];
  if (active) {
    load_afrag<4>(a, sH, mt, l16, quad);
    zero4(accM);
    mfma_rows<4>(accM, a, wf_msg, gh, lane);
    epi(accM, bmsg, false, sT, mt, gh, quad, l16);
  }
  __syncthreads();  // bar A: t visible
  if (active) {
    zero4(accU);
    mfma_rows<4>(accU, a, wf_new, gh, lane);  // h-part, reuses A-frags
  }
  gather(sT, sAgg, sEf, sRowPtr, sEidx, WmBot, q16, c2);
  __syncthreads();  // bar B: agg visible; all sH/sT reads complete
  if (active) {
    short8 a2[4];
    load_afrag<4>(a2, sAgg, mt, l16, quad);
    mfma_rows<4>(accU, a2, wf_new + 4 * 4096, gh, lane);
    epi(accU, bnew, true, sH, mt, gh, quad, l16);
  }
  __syncthreads();  // bar C: new h visible
}

template<bool PRODUCT>
__global__ __launch_bounds__(NT, 4) void wln_fused(
    const void* __restrict__ Xin, const void* __restrict__ EFin,
    const int* __restrict__ SRC, const int* __restrict__ DST,
    const bf16* __restrict__ wf_proj, const float* __restrict__ bproj,
    const bf16* __restrict__ wf_msg, const float* __restrict__ bmsg,
    const float* __restrict__ WmBot,
    const bf16* __restrict__ wf_new, const float* __restrict__ bnew,
    const bf16* __restrict__ wf_msgd, const float* __restrict__ bmsgd,
    const float* __restrict__ WmdBot,
    const bf16* __restrict__ wf_newd, const float* __restrict__ bnewd,
    bf16* __restrict__ hr_global,
    const float* __restrict__ W1, const float* __restrict__ b1,
    const float* __restrict__ W2, const float* __restrict__ b2,
    const float* __restrict__ scores, float* __restrict__ out) {
  __shared__ bf16 sH[MROWS * LDA];
  __shared__ bf16 sT[MROWS * LDA];
  __shared__ bf16 sAgg[MROWS * LDA];
  __shared__ float sEf[ER_N * 8];
  __shared__ int sRowPtr[VV + 1];
  __shared__ int sCnt[VV];
  __shared__ int sScan[128];
  __shared__ int sSD[ER_N];
  __shared__ int sEidx[ER_N];
  __shared__ float sRed[NT];
  __shared__ float sG[H];

  const int tid = threadIdx.x;
  const int lane = tid & 63;
  const int wave = tid >> 6;               // 0..15
  const int quad = (lane >> 4) & 3, l16 = lane & 15;
  const int mt = wave >> 1, gh = wave & 1; // 7 m-tiles x 2 n-halves; waves 14,15 idle
  const bool active = (mt < 7);
  const int q16 = tid >> 6, c2 = tid & 63;
  const int c = blockIdx.x;
  const int no = c * VV;
  const long eo = (long)c * ER_N;

  // ---- stage edges + CSR build + edge feats + X -> sT ----
  if (tid < VV) sCnt[tid] = 0;
  __syncthreads();
  if (tid < ER_N) {
    int s = SRC[eo + tid] - no;
    int d = DST[eo + tid] - no;
    sSD[tid] = (d << 16) | s;
    atomicAdd(&sCnt[d], 1);
  }
  if (PRODUCT) {
    const float4* Ep = (const float4*)((const float*)EFin + eo * 8);
    for (int f = tid; f < 500; f += NT) ((float4*)sEf)[f] = Ep[f];
    const bf16* Xb = (const bf16*)Xin + (size_t)no * 96;
    for (int f = tid; f < 1200; f += NT) {  // 100 rows x 12 b128 groups
      int r = f / 12, g = f - r * 12;
      *(float4*)&sT[r * LDA + g * 8] = *(const float4*)(Xb + r * 96 + g * 8);
    }
  } else {
    const float* Ef = (const float*)EFin;
    for (int f = tid; f < ER_N * EDGE_IN_N; f += NT) {
      int e = f / EDGE_IN_N, k = f - e * EDGE_IN_N;
      sEf[e * 8 + k] = Ef[f];
    }
    const float* X = (const float*)Xin;
    for (int f = tid; f < VV * 96; f += NT) {
      int r = f / 96, cc = f - r * 96;
      float v = (cc < NODE_IN_N) ? X[r * NODE_IN_N + cc] : 0.f;
      sT[r * LDA + cc] = __float2bfloat16(v);
    }
  }
  __syncthreads();
  int myc = 0;
  if (tid < 128) {
    myc = (tid < VV) ? sCnt[tid] : 0;
    sScan[tid] = myc;
  }
  __syncthreads();
  for (int off = 1; off < 128; off <<= 1) {
    int x = (tid < 128 && tid >= off) ? sScan[tid - off] : 0;
    __syncthreads();
    if (tid < 128) sScan[tid] += x;
    __syncthreads();
  }
  if (tid < VV) {
    int ex = sScan[tid] - myc;
    sRowPtr[tid] = ex;
    sCnt[tid] = ex;  // cursor
  }
  if (tid == 0) sRowPtr[VV] = ER_N;
  __syncthreads();
  if (tid < ER_N) {
    int sd = sSD[tid];
    int p = atomicAdd(&sCnt[sd >> 16], 1);
    sEidx[p] = (sd & 0xffff) | (tid << 7);
  }
  __syncthreads();

  // ---- input projection: h = relu(X @ Wproj + bproj), KPAD=96 ----
  if (active) {
    short8 a[3];
    floatx4 acc[4];
    load_afrag<3>(a, sT, mt, l16, quad);
    zero4(acc);
    mfma_rows<3>(acc, a, wf_proj, gh, lane);
    epi(acc, bproj, true, sH, mt, gh, quad, l16);
  }
  __syncthreads();

  // ---- 3 shared-weight encoder layers ----
  for (int l = 0; l < 3; ++l)
    wln_layer(sH, sT, sAgg, sEf, sRowPtr, sEidx, wf_msg, bmsg, WmBot, wf_new, bnew,
              active, lane, mt, gh, quad, l16, q16, c2);

  if (!PRODUCT) {
    for (int f = tid; f < VV * H; f += NT)
      hr_global[f] = sH[(f >> 7) * LDA + (f & 127)];
    return;
  }

  // ---- diff against broadcast reactant ----
  for (int f = tid; f < VV * H; f += NT) {
    int r = f >> 7, j = f & 127;
    float v = __bfloat162float(sH[r * LDA + j]) - __bfloat162float(hr_global[f]);
    sH[r * LDA + j] = __float2bfloat16(v);
  }
  __syncthreads();

  // ---- diff WLN layer ----
  wln_layer(sH, sT, sAgg, sEf, sRowPtr, sEidx, wf_msgd, bmsgd, WmdBot, wf_newd, bnewd,
            active, lane, mt, gh, quad, l16, q16, c2);

  // ---- head: sum-pool + MLP + candidate score ----
  {
    int j = tid & 127, qq = tid >> 7;  // 8 row-groups: {13,13,13,13,12,12,12,12}
    int start = qq * 12 + ((qq < 4) ? qq : 4);
    int cnt = (qq < 4) ? 13 : 12;
    float p = 0.f;
    for (int v = start; v < start + cnt; ++v)
      p += __bfloat162float(sH[v * LDA + j]);
    sRed[tid] = p;
  }
  __syncthreads();
  if (tid < H) {
    float s = 0.f;
#pragma unroll
    for (int q = 0; q < 8; ++q) s += sRed[q * 128 + tid];
    sG[tid] = s;
  }
  __syncthreads();
  {
    int j = tid & 127, qq = tid >> 7;
    float a = 0.f;
    for (int k = qq * 16; k < qq * 16 + 16; ++k)
      a = fmaf(sG[k], W1[(size_t)k * H + j], a);
    sRed[tid] = a;
  }
  __syncthreads();
  if (tid < H) {
    float m = b1[tid];
#pragma unroll
    for (int q = 0; q < 8; ++q) m += sRed[q * 128 + tid];
    sG[tid] = fmaxf(m, 0.f) * W2[tid];
  }
  __syncthreads();
  for (int s2 = 64; s2 > 0; s2 >>= 1) {
    if (tid < s2) sG[tid] += sG[tid + s2];
    __syncthreads();
  }
  if (tid == 0) out[c] = sG[0] + b2[0] + scores[c];
}

extern "C" void kernel_launch(void* const* d_in, const int* in_sizes, int n_in,
                              void* d_out, int out_size, void* d_ws, size_t ws_size,
                              hipStream_t stream) {
  const float* Xr  = (const float*)d_in[0];
  const float* Ere = (const float*)d_in[1];
  const float* Xp  = (const float*)d_in[2];
  const float* Epe = (const float*)d_in[3];
  const float* sc  = (const float*)d_in[4];
  const float* Wp  = (const float*)d_in[5];
  const float* bp  = (const float*)d_in[6];
  const float* Wm  = (const float*)d_in[7];
  const float* bm  = (const float*)d_in[8];
  const float* Wn  = (const float*)d_in[9];
  const float* bn  = (const float*)d_in[10];
  const float* Wmd = (const float*)d_in[11];
  const float* bmd = (const float*)d_in[12];
  const float* Wnd = (const float*)d_in[13];
  const float* bnd = (const float*)d_in[14];
  const float* W1  = (const float*)d_in[15];
  const float* b1  = (const float*)d_in[16];
  const float* W2  = (const float*)d_in[17];
  const float* b2  = (const float*)d_in[18];
  const int* rsrc  = (const int*)d_in[19];
  const int* rdst  = (const int*)d_in[20];
  const int* psrc  = (const int*)d_in[21];
  const int* pdst  = (const int*)d_in[22];

  bf16* wf_proj = (bf16*)d_ws;            // 27*4096 total frag elems
  bf16* wf_msg  = wf_proj + 3 * 4096;
  bf16* wf_new  = wf_msg + 4 * 4096;
  bf16* wf_msgd = wf_new + 8 * 4096;
  bf16* wf_newd = wf_msgd + 4 * 4096;
  bf16* hr      = wf_newd + 8 * 4096;     // VV*H
  bf16* Xbf     = hr + VV * H;            // 100000*96 bf16
  float* Epad   = (float*)(Xbf + (size_t)NP_TOT * 96);  // 250000*8 fp32

  float* out = (float*)d_out;

  // ---- merged prep: weights + X + E ----
  {
    long total = (long)PREP_W + (long)PREP_X + (long)NP_TOT * 20;
    int blocks = (int)((total + 255) / 256);
    prep_all<<<blocks, 256, 0, stream>>>(Wp, Wm, Wn, Wmd, Wnd, Xp, Epe,
                                         wf_proj, Xbf, Epad);
  }

  // ---- reactant (1 block) then products (1000 blocks) ----
  wln_fused<false><<<1, NT, 0, stream>>>(
      Xr, Ere, rsrc, rdst, wf_proj, bp, wf_msg, bm, Wm + H * H, wf_new, bn,
      wf_msgd, bmd, Wmd + H * H, wf_newd, bnd, hr, W1, b1, W2, b2, sc, out);
  wln_fused<true><<<CC, NT, 0, stream>>>(
      Xbf, Epad, psrc, pdst, wf_proj, bp, wf_msg, bm, Wm + H * H, wf_new, bn,
      wf_msgd, bmd, Wmd + H * H, wf_newd, bnd, hr, W1, b1, W2, b2, sc, out);
}

// Round 8
// 306.684 us; speedup vs baseline: 2.2323x; 2.2323x over previous
//
#include <hip/hip_runtime.h>
#include <hip/hip_bf16.h>
#include <cstdint>

#define H 128
#define VV 100
#define CC 1000
#define ER_N 250
#define NODE_IN_N 82
#define EDGE_IN_N 6
#define MROWS 112   // 7 m-tiles of 16
#define LDA 136     // bf16 row stride: keeps b128 16B-aligned, 2-way banks (free)
#define NT 1024     // 16 waves per block
#define NP_TOT 100000

typedef short short8 __attribute__((ext_vector_type(8)));
typedef float floatx4 __attribute__((ext_vector_type(4)));
typedef __hip_bfloat16 bf16;

// ================= prep: weights -> B-frag bf16; Xp -> bf16 padded; Epe -> padded ====
#define PREP_W (27 * 4096)
#define PREP_X (NP_TOT * 48)
__global__ __launch_bounds__(256) void prep_all(
    const float* __restrict__ Wp, const float* __restrict__ Wm,
    const float* __restrict__ Wn, const float* __restrict__ Wmd,
    const float* __restrict__ Wnd, const float* __restrict__ Xp,
    const float* __restrict__ Epe,
    bf16* __restrict__ wfrag, bf16* __restrict__ Xbf, float* __restrict__ Epad) {
  long idx = (long)blockIdx.x * 256 + threadIdx.x;
  if (idx < PREP_W) {
    const float* W;
    int Ksrc;
    long local = idx;
    if (idx < 3 * 4096)       { W = Wp;  Ksrc = NODE_IN_N; }
    else if (idx < 7 * 4096)  { W = Wm;  Ksrc = H;     local -= 3 * 4096; }
    else if (idx < 15 * 4096) { W = Wn;  Ksrc = 2 * H; local -= 7 * 4096; }
    else if (idx < 19 * 4096) { W = Wmd; Ksrc = H;     local -= 15 * 4096; }
    else                      { W = Wnd; Ksrc = 2 * H; local -= 19 * 4096; }
    int j = local & 7, lane = (local >> 3) & 63, nt = (local >> 9) & 7, kc = local >> 12;
    int k = kc * 32 + ((lane >> 4) & 3) * 8 + j;
    int n = nt * 16 + (lane & 15);
    float v = (k < Ksrc) ? W[(size_t)k * H + n] : 0.f;
    wfrag[idx] = __float2bfloat16(v);
    return;
  }
  idx -= PREP_W;
  if (idx < (long)PREP_X) {  // Xp -> bf16 [NP_TOT][96] (zero-padded cols)
    long r = idx / 48;
    int p = (int)(idx - r * 48);
    int c0 = 2 * p;
    float v0 = (c0 < NODE_IN_N) ? Xp[r * NODE_IN_N + c0] : 0.f;
    float v1 = (c0 + 1 < NODE_IN_N) ? Xp[r * NODE_IN_N + c0 + 1] : 0.f;
    __hip_bfloat162 pk;
    pk.x = __float2bfloat16(v0);
    pk.y = __float2bfloat16(v1);
    *(__hip_bfloat162*)&Xbf[r * 96 + c0] = pk;
    return;
  }
  idx -= (long)PREP_X;
  if (idx < (long)NP_TOT * 20) {  // Epe -> fp32 [250000][8]
    long e = idx >> 3;
    int k = (int)(idx & 7);
    Epad[idx] = (k < EDGE_IN_N) ? Epe[e * EDGE_IN_N + k] : 0.f;
  }
}

// ============ GEMM helpers: wave = (mh<<3)|nt8 ; 1 n-tile x 3-4 m-tiles per wave =====
template<int CHUNKS>
__device__ __forceinline__ void load_bfrag(short8 b[CHUNKS], const bf16* __restrict__ Wf,
                                           int nt8, int lane) {
#pragma unroll
  for (int kc = 0; kc < CHUNKS; ++kc)
    b[kc] = *(const short8*)(Wf + ((size_t)((kc * 8 + nt8) * 64 + lane)) * 8);
}

template<int CHUNKS>
__device__ __forceinline__ void mfma_mt(floatx4 acc[4], const short8 b[CHUNKS],
                                        const bf16* A, int m0, int mc,
                                        int l16, int quad) {
#pragma unroll
  for (int kc = 0; kc < CHUNKS; ++kc)
#pragma unroll
    for (int mi = 0; mi < 4; ++mi)
      if (mi < mc) {
        short8 a = *(const short8*)(A + ((m0 + mi) * 16 + l16) * LDA + kc * 32 + quad * 8);
        acc[mi] = __builtin_amdgcn_mfma_f32_16x16x32_bf16(a, b[kc], acc[mi], 0, 0, 0);
      }
}

__device__ __forceinline__ void epi(floatx4 acc[4], const float* __restrict__ bias,
                                    bool relu, bf16* Out,
                                    int nt8, int m0, int mc, int quad, int l16) {
  int col = nt8 * 16 + l16;
  float bb = bias[col];
#pragma unroll
  for (int mi = 0; mi < 4; ++mi)
    if (mi < mc)
#pragma unroll
      for (int r = 0; r < 4; ++r) {
        float v = acc[mi][r] + bb;
        if (relu) v = fmaxf(v, 0.f);
        Out[((m0 + mi) * 16 + quad * 4 + r) * LDA + col] = __float2bfloat16(v);
      }
}

__device__ __forceinline__ void zero4(floatx4 acc[4]) {
#pragma unroll
  for (int mi = 0; mi < 4; ++mi) acc[mi] = (floatx4){0.f, 0.f, 0.f, 0.f};
}

// gather: thread (node q16+16i, col-pair c2) writes agg directly to sAgg
__device__ __forceinline__ void gather(const bf16* sT, bf16* sAgg, const float* sEf,
                                       const int* sRowPtr, const int* sEidx,
                                       const float* __restrict__ WmBot,
                                       int q16, int c2) {
  float wb[EDGE_IN_N][2];
#pragma unroll
  for (int k = 0; k < EDGE_IN_N; ++k) {
    float2 w2 = *(const float2*)&WmBot[k * H + 2 * c2];
    wb[k][0] = w2.x;
    wb[k][1] = w2.y;
  }
#pragma unroll
  for (int i = 0; i < 7; ++i) {
    int n = q16 + 16 * i;
    if (n < VV) {
      int p0 = sRowPtr[n], p1 = sRowPtr[n + 1];
      float a0 = 0.f, a1 = 0.f;
      for (int p = p0; p < p1; ++p) {
        int v = sEidx[p];
        int s = v & 127, e = v >> 7;
        uint32_t tt = *(const uint32_t*)&sT[s * LDA + 2 * c2];
        float u0 = __uint_as_float((tt & 0xffffu) << 16);
        float u1 = __uint_as_float((tt >> 16) << 16);
        float4 ea = *(const float4*)&sEf[e * 8];
        float2 eb = *(const float2*)&sEf[e * 8 + 4];
        u0 = fmaf(ea.x, wb[0][0], u0); u1 = fmaf(ea.x, wb[0][1], u1);
        u0 = fmaf(ea.y, wb[1][0], u0); u1 = fmaf(ea.y, wb[1][1], u1);
        u0 = fmaf(ea.z, wb[2][0], u0); u1 = fmaf(ea.z, wb[2][1], u1);
        u0 = fmaf(ea.w, wb[3][0], u0); u1 = fmaf(ea.w, wb[3][1], u1);
        u0 = fmaf(eb.x, wb[4][0], u0); u1 = fmaf(eb.x, wb[4][1], u1);
        u0 = fmaf(eb.y, wb[5][0], u0); u1 = fmaf(eb.y, wb[5][1], u1);
        a0 += fmaxf(u0, 0.f);
        a1 += fmaxf(u1, 0.f);
      }
      __hip_bfloat162 pk;
      pk.x = __float2bfloat16(a0);
      pk.y = __float2bfloat16(a1);
      *(__hip_bfloat162*)&sAgg[n * LDA + 2 * c2] = pk;
    }
  }
}

// one WLN layer: 3 barriers; B-frags register-prefetched across phases.
__device__ __forceinline__ void wln_layer(
    bf16* sH, bf16* sT, bf16* sAgg, const float* sEf,
    const int* sRowPtr, const int* sEidx,
    const bf16* __restrict__ wf_msg, const float* __restrict__ bmsg,
    const float* __restrict__ WmBot,
    const bf16* __restrict__ wf_new, const float* __restrict__ bnew,
    int lane, int nt8, int m0, int mc, int quad, int l16, int q16, int c2) {
  short8 bm_[4], bu1[4], bu2[4];
  floatx4 accM[4], accU[4];
  // phase 1: msg GEMM t = h @ Wm_top + bm
  load_bfrag<4>(bm_, wf_msg, nt8, lane);
  zero4(accM);
  mfma_mt<4>(accM, bm_, sH, m0, mc, l16, quad);
  load_bfrag<4>(bu1, wf_new, nt8, lane);           // prefetch upd-h B
  epi(accM, bmsg, false, sT, nt8, m0, mc, quad, l16);
  __syncthreads();  // bar A: t visible (prefetch drains here, in flight during wait)
  // phase 2: upd-h GEMM + gather
  zero4(accU);
  mfma_mt<4>(accU, bu1, sH, m0, mc, l16, quad);
  load_bfrag<4>(bu2, wf_new + 4 * 4096, nt8, lane); // prefetch upd-agg B
  gather(sT, sAgg, sEf, sRowPtr, sEidx, WmBot, q16, c2);
  __syncthreads();  // bar B: agg visible; all sH/sT reads complete
  // phase 3: upd-agg GEMM, write new h
  mfma_mt<4>(accU, bu2, sAgg, m0, mc, l16, quad);
  epi(accU, bnew, true, sH, nt8, m0, mc, quad, l16);
  __syncthreads();  // bar C: new h visible
}

template<bool PRODUCT>
__global__ __launch_bounds__(NT, 4) void wln_fused(
    const void* __restrict__ Xin, const void* __restrict__ EFin,
    const int* __restrict__ SRC, const int* __restrict__ DST,
    const bf16* __restrict__ wf_proj, const float* __restrict__ bproj,
    const bf16* __restrict__ wf_msg, const float* __restrict__ bmsg,
    const float* __restrict__ WmBot,
    const bf16* __restrict__ wf_new, const float* __restrict__ bnew,
    const bf16* __restrict__ wf_msgd, const float* __restrict__ bmsgd,
    const float* __restrict__ WmdBot,
    const bf16* __restrict__ wf_newd, const float* __restrict__ bnewd,
    bf16* __restrict__ hr_global,
    const float* __restrict__ W1, const float* __restrict__ b1,
    const float* __restrict__ W2, const float* __restrict__ b2,
    const float* __restrict__ scores, float* __restrict__ out) {
  __shared__ bf16 sH[MROWS * LDA];
  __shared__ bf16 sT[MROWS * LDA];
  __shared__ bf16 sAgg[MROWS * LDA];
  __shared__ float sEf[ER_N * 8];
  __shared__ int sRowPtr[VV + 1];
  __shared__ int sCnt[VV];
  __shared__ int sScan[128];
  __shared__ int sSD[ER_N];
  __shared__ int sEidx[ER_N];
  __shared__ float sRed[NT];
  __shared__ float sG[H];

  const int tid = threadIdx.x;
  const int lane = tid & 63;
  const int wave = tid >> 6;               // 0..15
  const int quad = (lane >> 4) & 3, l16 = lane & 15;
  const int nt8 = wave & 7, mh = wave >> 3; // 8 n-tiles x 2 m-halves, all waves active
  const int m0 = mh * 4, mc = mh ? 3 : 4;
  const int q16 = tid >> 6, c2 = tid & 63;
  const int c = blockIdx.x;
  const int no = c * VV;
  const long eo = (long)c * ER_N;

  // ---- stage edges + CSR build + edge feats + X -> sT ----
  if (tid < VV) sCnt[tid] = 0;
  __syncthreads();
  if (tid < ER_N) {
    int s = SRC[eo + tid] - no;
    int d = DST[eo + tid] - no;
    sSD[tid] = (d << 16) | s;
    atomicAdd(&sCnt[d], 1);
  }
  if (PRODUCT) {
    const float4* Ep = (const float4*)((const float*)EFin + eo * 8);
    for (int f = tid; f < 500; f += NT) ((float4*)sEf)[f] = Ep[f];
    const bf16* Xb = (const bf16*)Xin + (size_t)no * 96;
    for (int f = tid; f < 1200; f += NT) {  // 100 rows x 12 b128 groups
      int r = f / 12, g = f - r * 12;
      *(float4*)&sT[r * LDA + g * 8] = *(const float4*)(Xb + r * 96 + g * 8);
    }
  } else {
    const float* Ef = (const float*)EFin;
    for (int f = tid; f < ER_N * EDGE_IN_N; f += NT) {
      int e = f / EDGE_IN_N, k = f - e * EDGE_IN_N;
      sEf[e * 8 + k] = Ef[f];
    }
    const float* X = (const float*)Xin;
    for (int f = tid; f < VV * 96; f += NT) {
      int r = f / 96, cc = f - r * 96;
      float v = (cc < NODE_IN_N) ? X[r * NODE_IN_N + cc] : 0.f;
      sT[r * LDA + cc] = __float2bfloat16(v);
    }
  }
  __syncthreads();
  int myc = 0;
  if (tid < 128) {
    myc = (tid < VV) ? sCnt[tid] : 0;
    sScan[tid] = myc;
  }
  __syncthreads();
  for (int off = 1; off < 128; off <<= 1) {
    int x = (tid < 128 && tid >= off) ? sScan[tid - off] : 0;
    __syncthreads();
    if (tid < 128) sScan[tid] += x;
    __syncthreads();
  }
  if (tid < VV) {
    int ex = sScan[tid] - myc;
    sRowPtr[tid] = ex;
    sCnt[tid] = ex;  // cursor
  }
  if (tid == 0) sRowPtr[VV] = ER_N;
  __syncthreads();
  if (tid < ER_N) {
    int sd = sSD[tid];
    int p = atomicAdd(&sCnt[sd >> 16], 1);
    sEidx[p] = (sd & 0xffff) | (tid << 7);
  }
  __syncthreads();

  // ---- input projection: h = relu(X @ Wproj + bproj), KPAD=96 ----
  {
    short8 bp_[3];
    floatx4 acc[4];
    load_bfrag<3>(bp_, wf_proj, nt8, lane);
    zero4(acc);
    mfma_mt<3>(acc, bp_, sT, m0, mc, l16, quad);
    epi(acc, bproj, true, sH, nt8, m0, mc, quad, l16);
  }
  __syncthreads();

  // ---- 3 shared-weight encoder layers ----
  for (int l = 0; l < 3; ++l)
    wln_layer(sH, sT, sAgg, sEf, sRowPtr, sEidx, wf_msg, bmsg, WmBot, wf_new, bnew,
              lane, nt8, m0, mc, quad, l16, q16, c2);

  if (!PRODUCT) {
    for (int f = tid; f < VV * H; f += NT)
      hr_global[f] = sH[(f >> 7) * LDA + (f & 127)];
    return;
  }

  // ---- diff against broadcast reactant ----
  for (int f = tid; f < VV * H; f += NT) {
    int r = f >> 7, j = f & 127;
    float v = __bfloat162float(sH[r * LDA + j]) - __bfloat162float(hr_global[f]);
    sH[r * LDA + j] = __float2bfloat16(v);
  }
  __syncthreads();

  // ---- diff WLN layer ----
  wln_layer(sH, sT, sAgg, sEf, sRowPtr, sEidx, wf_msgd, bmsgd, WmdBot, wf_newd, bnewd,
            lane, nt8, m0, mc, quad, l16, q16, c2);

  // ---- head: sum-pool + MLP + candidate score ----
  {
    int j = tid & 127, qq = tid >> 7;  // 8 row-groups: {13,13,13,13,12,12,12,12}
    int start = qq * 12 + ((qq < 4) ? qq : 4);
    int cnt = (qq < 4) ? 13 : 12;
    float p = 0.f;
    for (int v = start; v < start + cnt; ++v)
      p += __bfloat162float(sH[v * LDA + j]);
    sRed[tid] = p;
  }
  __syncthreads();
  if (tid < H) {
    float s = 0.f;
#pragma unroll
    for (int q = 0; q < 8; ++q) s += sRed[q * 128 + tid];
    sG[tid] = s;
  }
  __syncthreads();
  {
    int j = tid & 127, qq = tid >> 7;
    float a = 0.f;
    for (int k = qq * 16; k < qq * 16 + 16; ++k)
      a = fmaf(sG[k], W1[(size_t)k * H + j], a);
    sRed[tid] = a;
  }
  __syncthreads();
  if (tid < H) {
    float m = b1[tid];
#pragma unroll
    for (int q = 0; q < 8; ++q) m += sRed[q * 128 + tid];
    sG[tid] = fmaxf(m, 0.f) * W2[tid];
  }
  __syncthreads();
  for (int s2 = 64; s2 > 0; s2 >>= 1) {
    if (tid < s2) sG[tid] += sG[tid + s2];
    __syncthreads();
  }
  if (tid == 0) out[c] = sG[0] + b2[0] + scores[c];
}

extern "C" void kernel_launch(void* const* d_in, const int* in_sizes, int n_in,
                              void* d_out, int out_size, void* d_ws, size_t ws_size,
                              hipStream_t stream) {
  const float* Xr  = (const float*)d_in[0];
  const float* Ere = (const float*)d_in[1];
  const float* Xp  = (const float*)d_in[2];
  const float* Epe = (const float*)d_in[3];
  const float* sc  = (const float*)d_in[4];
  const float* Wp  = (const float*)d_in[5];
  const float* bp  = (const float*)d_in[6];
  const float* Wm  = (const float*)d_in[7];
  const float* bm  = (const float*)d_in[8];
  const float* Wn  = (const float*)d_in[9];
  const float* bn  = (const float*)d_in[10];
  const float* Wmd = (const float*)d_in[11];
  const float* bmd = (const float*)d_in[12];
  const float* Wnd = (const float*)d_in[13];
  const float* bnd = (const float*)d_in[14];
  const float* W1  = (const float*)d_in[15];
  const float* b1  = (const float*)d_in[16];
  const float* W2  = (const float*)d_in[17];
  const float* b2  = (const float*)d_in[18];
  const int* rsrc  = (const int*)d_in[19];
  const int* rdst  = (const int*)d_in[20];
  const int* psrc  = (const int*)d_in[21];
  const int* pdst  = (const int*)d_in[22];

  bf16* wf_proj = (bf16*)d_ws;            // 27*4096 total frag elems
  bf16* wf_msg  = wf_proj + 3 * 4096;
  bf16* wf_new  = wf_msg + 4 * 4096;
  bf16* wf_msgd = wf_new + 8 * 4096;
  bf16* wf_newd = wf_msgd + 4 * 4096;
  bf16* hr      = wf_newd + 8 * 4096;     // VV*H
  bf16* Xbf     = hr + VV * H;            // 100000*96 bf16
  float* Epad   = (float*)(Xbf + (size_t)NP_TOT * 96);  // 250000*8 fp32

  float* out = (float*)d_out;

  // ---- merged prep: weights + X + E ----
  {
    long total = (long)PREP_W + (long)PREP_X + (long)NP_TOT * 20;
    int blocks = (int)((total + 255) / 256);
    prep_all<<<blocks, 256, 0, stream>>>(Wp, Wm, Wn, Wmd, Wnd, Xp, Epe,
                                         wf_proj, Xbf, Epad);
  }

  // ---- reactant (1 block) then products (1000 blocks) ----
  wln_fused<false><<<1, NT, 0, stream>>>(
      Xr, Ere, rsrc, rdst, wf_proj, bp, wf_msg, bm, Wm + H * H, wf_new, bn,
      wf_msgd, bmd, Wmd + H * H, wf_newd, bnd, hr, W1, b1, W2, b2, sc, out);
  wln_fused<true><<<CC, NT, 0, stream>>>(
      Xbf, Epad, psrc, pdst, wf_proj, bp, wf_msg, bm, Wm + H * H, wf_new, bn,
      wf_msgd, bmd, Wmd + H * H, wf_newd, bnd, hr, W1, b1, W2, b2, sc, out);
}